// Round 9
// baseline (222.861 us; speedup 1.0000x reference)
//
#include <hip/hip_runtime.h>
#include <cstdint>

#define HW  128
#define NCH 256
#define NOC 18      // G*K*K
#define PLANE (HW * HW)
#define EPSBN 1e-5f

typedef __attribute__((ext_vector_type(8)))  short bf16x8;
typedef __attribute__((ext_vector_type(16))) float f32x16;

__device__ __forceinline__ unsigned short f2bf(float f) {
    union { float f; uint32_t u; } c; c.f = f;
    uint32_t u = c.u;
    uint32_t r = u + 0x7FFFu + ((u >> 16) & 1u);   // RNE
    return (unsigned short)(r >> 16);
}

// ------------- Kernel W: pack weights -> wB[tap][ic>>3][oc(32 pad)][ic&7] bf16
__global__ __launch_bounds__(256) void pasa_wprep(
    const float* __restrict__ w, unsigned short* __restrict__ wB)
{
    int idx = blockIdx.x * 256 + threadIdx.x;      // 9*32*32*8 = 73728
    int icl = idx & 7;
    int oc  = (idx >> 3) & 31;
    int icb = (idx >> 8) & 31;
    int tap = idx >> 13;
    int ic  = icb * 8 + icl;
    float v = (oc < NOC) ? w[((size_t)oc * NCH + ic) * 9 + tap] : 0.0f;
    wB[idx] = f2bf(v);
}

// ------------- Kernel C: x NCHW fp32 -> xc NHWC bf16 -----------------------
// grid 2048 = n(8) x y(128) x chhalf(2); block 256: px=t&127, h=t>>7.
// Thread: 64 channels at one (n,y,px) -> writes ONE full 128B line.
__global__ __launch_bounds__(256) void pasa_cvt(
    const float* __restrict__ x, unsigned short* __restrict__ xc)
{
    int flat = blockIdx.x;
    const int half = flat & 1;
    const int y    = (flat >> 1) & 127;
    const int n    = flat >> 8;

    const int px = threadIdx.x & 127;
    const int h  = threadIdx.x >> 7;
    const int c0 = half * 128 + h * 64;

    const float* xp = x + ((size_t)n * NCH) * PLANE + (size_t)y * HW + px;
    unsigned short* op = xc + (((size_t)n * HW + y) * HW + px) * NCH + c0;

    #pragma unroll
    for (int g = 0; g < 8; ++g) {
        float v[8];
        #pragma unroll
        for (int j = 0; j < 8; ++j)
            v[j] = xp[(size_t)(c0 + g * 8 + j) * PLANE];
        int4 d;
        d.x = (uint32_t)f2bf(v[0]) | ((uint32_t)f2bf(v[1]) << 16);
        d.y = (uint32_t)f2bf(v[2]) | ((uint32_t)f2bf(v[3]) << 16);
        d.z = (uint32_t)f2bf(v[4]) | ((uint32_t)f2bf(v[5]) << 16);
        d.w = (uint32_t)f2bf(v[6]) | ((uint32_t)f2bf(v[7]) << 16);
        *(int4*)(op + g * 8) = d;
    }
}

// ------------- Kernel A: implicit-GEMM conv + BN + softmax (unchanged R8) --
__global__ __launch_bounds__(256, 4) void pasa_conv_mfma(
    const unsigned short* __restrict__ xc, const unsigned short* __restrict__ wB,
    const float* __restrict__ gamma, const float* __restrict__ beta,
    const float* __restrict__ rmean, const float* __restrict__ rvar,
    float* __restrict__ sigma)
{
    int flat = blockIdx.x;                 // [0,1024)
    int nf   = (flat & 7) * 128 + (flat >> 3);   // XCD owns one image
    const int n = nf >> 7;
    const int y = nf & 127;

    const int lane = threadIdx.x & 63;
    const int wv   = threadIdx.x >> 6;     // px tile
    const int m    = lane & 31;
    const int hi   = lane >> 5;

    const int p0 = wv * 32 + m;
    int pxv[3];
    pxv[0] = (p0 == 0)   ? 1   : p0 - 1;   // reflect
    pxv[1] = p0;
    pxv[2] = (p0 == 127) ? 126 : p0 + 1;

    int gy[3];
    gy[0] = (y == 0)   ? 1   : y - 1;
    gy[1] = y;
    gy[2] = (y == 127) ? 126 : y + 1;

    const char* xn = (const char*)xc + (size_t)n * HW * HW * NCH * 2;
    const char* base[3][3];
    #pragma unroll
    for (int dy = 0; dy < 3; ++dy)
        #pragma unroll
        for (int dx = 0; dx < 3; ++dx)
            base[dy][dx] = xn + (((size_t)gy[dy] * HW + pxv[dx]) * NCH + hi * 8) * 2;

    const char* wb = (const char*)wB;

    f32x16 acc;
    #pragma unroll
    for (int i = 0; i < 16; ++i) acc[i] = 0.0f;

    #pragma unroll
    for (int chunk = 0; chunk < 4; ++chunk) {
        const int co = chunk * 128;        // 64 ic * 2B
        #pragma unroll
        for (int dy = 0; dy < 3; ++dy) {
            #pragma unroll
            for (int dx = 0; dx < 3; ++dx) {
                const int tap = dy * 3 + dx;
                const char* bp = base[dy][dx] + co;
                const char* wp = wb + (((size_t)(tap * 32 + chunk * 8 + hi) * 32 + m) << 4);
                bf16x8 x0 = *(const bf16x8*)(bp);
                bf16x8 w0 = *(const bf16x8*)(wp);
                acc = __builtin_amdgcn_mfma_f32_32x32x16_bf16(w0, x0, acc, 0, 0, 0);
                bf16x8 x1 = *(const bf16x8*)(bp + 32);
                bf16x8 w1 = *(const bf16x8*)(wp + 1024);
                acc = __builtin_amdgcn_mfma_f32_32x32x16_bf16(w1, x1, acc, 0, 0, 0);
                bf16x8 x2 = *(const bf16x8*)(bp + 64);
                bf16x8 w2 = *(const bf16x8*)(wp + 2048);
                acc = __builtin_amdgcn_mfma_f32_32x32x16_bf16(w2, x2, acc, 0, 0, 0);
                bf16x8 x3 = *(const bf16x8*)(bp + 96);
                bf16x8 w3 = *(const bf16x8*)(wp + 3072);
                acc = __builtin_amdgcn_mfma_f32_32x32x16_bf16(w3, x3, acc, 0, 0, 0);
            }
        }
    }

    // C/D layout: col(px)=lane&31, row(oc)=(r&3)+8*(r>>2)+4*hi
    float vals[16];
    float mx = -3.0e38f;
    #pragma unroll
    for (int r = 0; r < 16; ++r) {
        int oc = (r & 3) + 8 * (r >> 2) + 4 * hi;
        float v = -3.0e38f;
        if (oc < NOC) {
            float sc = gamma[oc] * rsqrtf(rvar[oc] + EPSBN);
            float b  = beta[oc] - rmean[oc] * sc;
            v = fmaf(acc[r], sc, b);
        }
        vals[r] = v;
        mx = fmaxf(mx, v);
    }
    mx = fmaxf(mx, __shfl_xor(mx, 32));
    float s = 0.0f;
    #pragma unroll
    for (int r = 0; r < 16; ++r) {
        int oc = (r & 3) + 8 * (r >> 2) + 4 * hi;
        float e = (oc < NOC) ? __expf(vals[r] - mx) : 0.0f;
        vals[r] = e;
        s += e;
    }
    s += __shfl_xor(s, 32);
    const float inv = 1.0f / s;

    float* so = sigma + (size_t)n * NOC * PLANE + (size_t)y * HW + p0;
    #pragma unroll
    for (int r = 0; r < 16; ++r) {
        int oc = (r & 3) + 8 * (r >> 2) + 4 * hi;
        if (oc < NOC) so[(size_t)oc * PLANE] = vals[r] * inv;
    }
}

// ------------- Kernel B: pooling with explicit 2-deep channel pipeline -----
// grid 2048 (n8 x chsplit8 x yq32), 256 thr: q=tid&31 (px quad),
// r=(tid>>5)&3 (row), s=tid>>7 (group). 16 ch/thread, double-buffered loads.
struct Ld9 {
    float a0, a1, b0, b1, c0, c1;
    float4 ma, mb, mc;
};

__global__ __launch_bounds__(256, 4) void pasa_pool(
    const float* __restrict__ x, const float* __restrict__ sigma,
    float* __restrict__ out)
{
    int flat = blockIdx.x;                 // [0,2048)
    int nf   = (flat & 7) * 256 + (flat >> 3);   // XCD owns one image
    const int n       = nf >> 8;
    const int chsplit = (nf >> 5) & 7;
    const int yq      = nf & 31;

    const int q = threadIdx.x & 31;
    const int r = (threadIdx.x >> 5) & 3;
    const int s = threadIdx.x >> 7;        // group 0/1

    const int y   = yq * 4 + r;
    const int px0 = q * 4;

    const int ym = (y == 0)      ? 1      : y - 1;
    const int yp = (y == HW - 1) ? HW - 2 : y + 1;
    const int lx = (px0 == 0)        ? 1      : px0 - 1;
    const int rx = (px0 + 4 > HW - 1)? HW - 2 : px0 + 4;

    const size_t ymO = (size_t)ym * HW;
    const size_t yO  = (size_t)y  * HW;
    const size_t ypO = (size_t)yp * HW;

    const float* sg = sigma + ((size_t)n * NOC + s * 9) * PLANE
                            + (size_t)y * HW + px0;
    float sgv[9][4];
    #pragma unroll
    for (int k = 0; k < 9; ++k) {
        float4 t = *(const float4*)(sg + (size_t)k * PLANE);
        sgv[k][0] = t.x; sgv[k][1] = t.y; sgv[k][2] = t.z; sgv[k][3] = t.w;
    }

    const int c0 = s * 128 + chsplit * 16;
    const float* xn = x + (size_t)n * NCH * PLANE;
    float*       on = out + (size_t)n * NCH * PLANE;

#define LOAD9(ch, L) do {                                               \
        const float* xcp = xn + (size_t)(ch) * PLANE;                   \
        (L).a0 = xcp[ymO + lx];                                         \
        (L).ma = *(const float4*)(xcp + ymO + px0);                     \
        (L).a1 = xcp[ymO + rx];                                         \
        (L).b0 = xcp[yO + lx];                                          \
        (L).mb = *(const float4*)(xcp + yO + px0);                      \
        (L).b1 = xcp[yO + rx];                                          \
        (L).c0 = xcp[ypO + lx];                                         \
        (L).mc = *(const float4*)(xcp + ypO + px0);                     \
        (L).c1 = xcp[ypO + rx];                                         \
    } while (0)

#define FMASTORE(ch, L) do {                                            \
        float ov[4] = {0.f, 0.f, 0.f, 0.f};                             \
        {                                                               \
            float wv[6] = {(L).a0, (L).ma.x, (L).ma.y, (L).ma.z, (L).ma.w, (L).a1}; \
            _Pragma("unroll") for (int j = 0; j < 4; ++j)               \
                _Pragma("unroll") for (int dx = 0; dx < 3; ++dx)        \
                    ov[j] = fmaf(wv[j + dx], sgv[dx][j], ov[j]);        \
        }                                                               \
        {                                                               \
            float wv[6] = {(L).b0, (L).mb.x, (L).mb.y, (L).mb.z, (L).mb.w, (L).b1}; \
            _Pragma("unroll") for (int j = 0; j < 4; ++j)               \
                _Pragma("unroll") for (int dx = 0; dx < 3; ++dx)        \
                    ov[j] = fmaf(wv[j + dx], sgv[3 + dx][j], ov[j]);    \
        }                                                               \
        {                                                               \
            float wv[6] = {(L).c0, (L).mc.x, (L).mc.y, (L).mc.z, (L).mc.w, (L).c1}; \
            _Pragma("unroll") for (int j = 0; j < 4; ++j)               \
                _Pragma("unroll") for (int dx = 0; dx < 3; ++dx)        \
                    ov[j] = fmaf(wv[j + dx], sgv[6 + dx][j], ov[j]);    \
        }                                                               \
        float4 o4 = { ov[0], ov[1], ov[2], ov[3] };                     \
        *(float4*)(on + (size_t)(ch) * PLANE + yO + px0) = o4;          \
    } while (0)

    Ld9 A, B;
    LOAD9(c0, A);
    #pragma unroll
    for (int cc = 0; cc < 16; cc += 2) {
        LOAD9(c0 + cc + 1, B);
        FMASTORE(c0 + cc, A);
        if (cc + 2 < 16) LOAD9(c0 + cc + 2, A);
        FMASTORE(c0 + cc + 1, B);
    }
#undef LOAD9
#undef FMASTORE
}

extern "C" void kernel_launch(void* const* d_in, const int* in_sizes, int n_in,
                              void* d_out, int out_size, void* d_ws, size_t ws_size,
                              hipStream_t stream) {
    const float* x     = (const float*)d_in[0];
    const float* w     = (const float*)d_in[1];
    const float* gamma = (const float*)d_in[2];
    const float* beta  = (const float*)d_in[3];
    const float* rmean = (const float*)d_in[4];
    const float* rvar  = (const float*)d_in[5];
    float* out   = (float*)d_out;
    float* sigma = (float*)d_ws;                 // 8*18*16384*4 = 9.44 MB

    // scratch in d_out (pool fully overwrites d_out last, after conv reads):
    //   xc (NHWC bf16): 8*128*128*256*2 = 67.1 MB at offset 0
    //   wB: 147 KB at byte offset 80 MB
    unsigned short* xcb = (unsigned short*)d_out;
    unsigned short* wB  = (unsigned short*)((char*)d_out + (size_t)80 * 1024 * 1024);

    pasa_wprep<<<dim3(288), dim3(256), 0, stream>>>(w, wB);
    pasa_cvt<<<dim3(2048), dim3(256), 0, stream>>>(x, xcb);
    pasa_conv_mfma<<<dim3(1024), dim3(256), 0, stream>>>(
        xcb, wB, gamma, beta, rmean, rvar, sigma);
    pasa_pool<<<dim3(2048), dim3(256), 0, stream>>>(x, sigma, out);
}

// Round 10
// 219.003 us; speedup vs baseline: 1.0176x; 1.0176x over previous
//
#include <hip/hip_runtime.h>
#include <cstdint>

#define HW  128
#define NCH 256
#define NOC 18      // G*K*K
#define PLANE (HW * HW)
#define EPSBN 1e-5f

typedef __attribute__((ext_vector_type(8)))  short bf16x8;
typedef __attribute__((ext_vector_type(16))) float f32x16;

__device__ __forceinline__ unsigned short f2bf(float f) {
    union { float f; uint32_t u; } c; c.f = f;
    uint32_t u = c.u;
    uint32_t r = u + 0x7FFFu + ((u >> 16) & 1u);   // RNE
    return (unsigned short)(r >> 16);
}

// ------------- Kernel W: pack weights -> wB[tap][ic>>3][oc(32 pad)][ic&7] bf16
__global__ __launch_bounds__(256) void pasa_wprep(
    const float* __restrict__ w, unsigned short* __restrict__ wB)
{
    int idx = blockIdx.x * 256 + threadIdx.x;      // 9*32*32*8 = 73728
    int icl = idx & 7;
    int oc  = (idx >> 3) & 31;
    int icb = (idx >> 8) & 31;
    int tap = idx >> 13;
    int ic  = icb * 8 + icl;
    float v = (oc < NOC) ? w[((size_t)oc * NCH + ic) * 9 + tap] : 0.0f;
    wB[idx] = f2bf(v);
}

// ------------- Kernel C: x NCHW fp32 -> xc NHWC bf16 -----------------------
// grid 2048 = n(8) x y(128) x chhalf(2); block 256: px=t&127, h=t>>7.
// Each thread: ALL 64 loads issued up-front (64 outstanding -> latency
// hidden), then pack + 8 contiguous 16B stores = one full 128B line.
__global__ __launch_bounds__(256) void pasa_cvt(
    const float* __restrict__ x, unsigned short* __restrict__ xc)
{
    int flat = blockIdx.x;
    const int half = flat & 1;
    const int y    = (flat >> 1) & 127;
    const int n    = flat >> 8;

    const int px = threadIdx.x & 127;
    const int h  = threadIdx.x >> 7;
    const int c0 = half * 128 + h * 64;

    const float* xp = x + ((size_t)n * NCH + c0) * PLANE + (size_t)y * HW + px;
    unsigned short* op = xc + (((size_t)n * HW + y) * HW + px) * NCH + c0;

    float v[64];
    #pragma unroll
    for (int j = 0; j < 64; ++j)
        v[j] = xp[(size_t)j * PLANE];

    #pragma unroll
    for (int g = 0; g < 8; ++g) {
        int4 d;
        d.x = (uint32_t)f2bf(v[g * 8 + 0]) | ((uint32_t)f2bf(v[g * 8 + 1]) << 16);
        d.y = (uint32_t)f2bf(v[g * 8 + 2]) | ((uint32_t)f2bf(v[g * 8 + 3]) << 16);
        d.z = (uint32_t)f2bf(v[g * 8 + 4]) | ((uint32_t)f2bf(v[g * 8 + 5]) << 16);
        d.w = (uint32_t)f2bf(v[g * 8 + 6]) | ((uint32_t)f2bf(v[g * 8 + 7]) << 16);
        *(int4*)(op + g * 8) = d;
    }
}

// ------------- Kernel A: implicit-GEMM conv + BN + softmax (unchanged R8) --
__global__ __launch_bounds__(256, 4) void pasa_conv_mfma(
    const unsigned short* __restrict__ xc, const unsigned short* __restrict__ wB,
    const float* __restrict__ gamma, const float* __restrict__ beta,
    const float* __restrict__ rmean, const float* __restrict__ rvar,
    float* __restrict__ sigma)
{
    int flat = blockIdx.x;                 // [0,1024)
    int nf   = (flat & 7) * 128 + (flat >> 3);   // XCD owns one image
    const int n = nf >> 7;
    const int y = nf & 127;

    const int lane = threadIdx.x & 63;
    const int wv   = threadIdx.x >> 6;     // px tile
    const int m    = lane & 31;
    const int hi   = lane >> 5;

    const int p0 = wv * 32 + m;
    int pxv[3];
    pxv[0] = (p0 == 0)   ? 1   : p0 - 1;   // reflect
    pxv[1] = p0;
    pxv[2] = (p0 == 127) ? 126 : p0 + 1;

    int gy[3];
    gy[0] = (y == 0)   ? 1   : y - 1;
    gy[1] = y;
    gy[2] = (y == 127) ? 126 : y + 1;

    const char* xn = (const char*)xc + (size_t)n * HW * HW * NCH * 2;
    const char* base[3][3];
    #pragma unroll
    for (int dy = 0; dy < 3; ++dy)
        #pragma unroll
        for (int dx = 0; dx < 3; ++dx)
            base[dy][dx] = xn + (((size_t)gy[dy] * HW + pxv[dx]) * NCH + hi * 8) * 2;

    const char* wb = (const char*)wB;

    f32x16 acc;
    #pragma unroll
    for (int i = 0; i < 16; ++i) acc[i] = 0.0f;

    #pragma unroll
    for (int chunk = 0; chunk < 4; ++chunk) {
        const int co = chunk * 128;        // 64 ic * 2B
        #pragma unroll
        for (int dy = 0; dy < 3; ++dy) {
            #pragma unroll
            for (int dx = 0; dx < 3; ++dx) {
                const int tap = dy * 3 + dx;
                const char* bp = base[dy][dx] + co;
                const char* wp = wb + (((size_t)(tap * 32 + chunk * 8 + hi) * 32 + m) << 4);
                bf16x8 x0 = *(const bf16x8*)(bp);
                bf16x8 w0 = *(const bf16x8*)(wp);
                acc = __builtin_amdgcn_mfma_f32_32x32x16_bf16(w0, x0, acc, 0, 0, 0);
                bf16x8 x1 = *(const bf16x8*)(bp + 32);
                bf16x8 w1 = *(const bf16x8*)(wp + 1024);
                acc = __builtin_amdgcn_mfma_f32_32x32x16_bf16(w1, x1, acc, 0, 0, 0);
                bf16x8 x2 = *(const bf16x8*)(bp + 64);
                bf16x8 w2 = *(const bf16x8*)(wp + 2048);
                acc = __builtin_amdgcn_mfma_f32_32x32x16_bf16(w2, x2, acc, 0, 0, 0);
                bf16x8 x3 = *(const bf16x8*)(bp + 96);
                bf16x8 w3 = *(const bf16x8*)(wp + 3072);
                acc = __builtin_amdgcn_mfma_f32_32x32x16_bf16(w3, x3, acc, 0, 0, 0);
            }
        }
    }

    // C/D layout: col(px)=lane&31, row(oc)=(r&3)+8*(r>>2)+4*hi
    float vals[16];
    float mx = -3.0e38f;
    #pragma unroll
    for (int r = 0; r < 16; ++r) {
        int oc = (r & 3) + 8 * (r >> 2) + 4 * hi;
        float v = -3.0e38f;
        if (oc < NOC) {
            float sc = gamma[oc] * rsqrtf(rvar[oc] + EPSBN);
            float b  = beta[oc] - rmean[oc] * sc;
            v = fmaf(acc[r], sc, b);
        }
        vals[r] = v;
        mx = fmaxf(mx, v);
    }
    mx = fmaxf(mx, __shfl_xor(mx, 32));
    float s = 0.0f;
    #pragma unroll
    for (int r = 0; r < 16; ++r) {
        int oc = (r & 3) + 8 * (r >> 2) + 4 * hi;
        float e = (oc < NOC) ? __expf(vals[r] - mx) : 0.0f;
        vals[r] = e;
        s += e;
    }
    s += __shfl_xor(s, 32);
    const float inv = 1.0f / s;

    float* so = sigma + (size_t)n * NOC * PLANE + (size_t)y * HW + p0;
    #pragma unroll
    for (int r = 0; r < 16; ++r) {
        int oc = (r & 3) + 8 * (r >> 2) + 4 * hi;
        if (oc < NOC) so[(size_t)oc * PLANE] = vals[r] * inv;
    }
}

// ------------- Kernel B: pooling with explicit 2-deep channel pipeline -----
struct Ld9 {
    float a0, a1, b0, b1, c0, c1;
    float4 ma, mb, mc;
};

__global__ __launch_bounds__(256, 4) void pasa_pool(
    const float* __restrict__ x, const float* __restrict__ sigma,
    float* __restrict__ out)
{
    int flat = blockIdx.x;                 // [0,2048)
    int nf   = (flat & 7) * 256 + (flat >> 3);   // XCD owns one image
    const int n       = nf >> 8;
    const int chsplit = (nf >> 5) & 7;
    const int yq      = nf & 31;

    const int q = threadIdx.x & 31;
    const int r = (threadIdx.x >> 5) & 3;
    const int s = threadIdx.x >> 7;        // group 0/1

    const int y   = yq * 4 + r;
    const int px0 = q * 4;

    const int ym = (y == 0)      ? 1      : y - 1;
    const int yp = (y == HW - 1) ? HW - 2 : y + 1;
    const int lx = (px0 == 0)        ? 1      : px0 - 1;
    const int rx = (px0 + 4 > HW - 1)? HW - 2 : px0 + 4;

    const size_t ymO = (size_t)ym * HW;
    const size_t yO  = (size_t)y  * HW;
    const size_t ypO = (size_t)yp * HW;

    const float* sg = sigma + ((size_t)n * NOC + s * 9) * PLANE
                            + (size_t)y * HW + px0;
    float sgv[9][4];
    #pragma unroll
    for (int k = 0; k < 9; ++k) {
        float4 t = *(const float4*)(sg + (size_t)k * PLANE);
        sgv[k][0] = t.x; sgv[k][1] = t.y; sgv[k][2] = t.z; sgv[k][3] = t.w;
    }

    const int c0 = s * 128 + chsplit * 16;
    const float* xn = x + (size_t)n * NCH * PLANE;
    float*       on = out + (size_t)n * NCH * PLANE;

#define LOAD9(ch, L) do {                                               \
        const float* xcp = xn + (size_t)(ch) * PLANE;                   \
        (L).a0 = xcp[ymO + lx];                                         \
        (L).ma = *(const float4*)(xcp + ymO + px0);                     \
        (L).a1 = xcp[ymO + rx];                                         \
        (L).b0 = xcp[yO + lx];                                          \
        (L).mb = *(const float4*)(xcp + yO + px0);                      \
        (L).b1 = xcp[yO + rx];                                          \
        (L).c0 = xcp[ypO + lx];                                         \
        (L).mc = *(const float4*)(xcp + ypO + px0);                     \
        (L).c1 = xcp[ypO + rx];                                         \
    } while (0)

#define FMASTORE(ch, L) do {                                            \
        float ov[4] = {0.f, 0.f, 0.f, 0.f};                             \
        {                                                               \
            float wv[6] = {(L).a0, (L).ma.x, (L).ma.y, (L).ma.z, (L).ma.w, (L).a1}; \
            _Pragma("unroll") for (int j = 0; j < 4; ++j)               \
                _Pragma("unroll") for (int dx = 0; dx < 3; ++dx)        \
                    ov[j] = fmaf(wv[j + dx], sgv[dx][j], ov[j]);        \
        }                                                               \
        {                                                               \
            float wv[6] = {(L).b0, (L).mb.x, (L).mb.y, (L).mb.z, (L).mb.w, (L).b1}; \
            _Pragma("unroll") for (int j = 0; j < 4; ++j)               \
                _Pragma("unroll") for (int dx = 0; dx < 3; ++dx)        \
                    ov[j] = fmaf(wv[j + dx], sgv[3 + dx][j], ov[j]);    \
        }                                                               \
        {                                                               \
            float wv[6] = {(L).c0, (L).mc.x, (L).mc.y, (L).mc.z, (L).mc.w, (L).c1}; \
            _Pragma("unroll") for (int j = 0; j < 4; ++j)               \
                _Pragma("unroll") for (int dx = 0; dx < 3; ++dx)        \
                    ov[j] = fmaf(wv[j + dx], sgv[6 + dx][j], ov[j]);    \
        }                                                               \
        float4 o4 = { ov[0], ov[1], ov[2], ov[3] };                     \
        *(float4*)(on + (size_t)(ch) * PLANE + yO + px0) = o4;          \
    } while (0)

    Ld9 A, B;
    LOAD9(c0, A);
    #pragma unroll
    for (int cc = 0; cc < 16; cc += 2) {
        LOAD9(c0 + cc + 1, B);
        FMASTORE(c0 + cc, A);
        if (cc + 2 < 16) LOAD9(c0 + cc + 2, A);
        FMASTORE(c0 + cc + 1, B);
    }
#undef LOAD9
#undef FMASTORE
}

extern "C" void kernel_launch(void* const* d_in, const int* in_sizes, int n_in,
                              void* d_out, int out_size, void* d_ws, size_t ws_size,
                              hipStream_t stream) {
    const float* x     = (const float*)d_in[0];
    const float* w     = (const float*)d_in[1];
    const float* gamma = (const float*)d_in[2];
    const float* beta  = (const float*)d_in[3];
    const float* rmean = (const float*)d_in[4];
    const float* rvar  = (const float*)d_in[5];
    float* out   = (float*)d_out;
    float* sigma = (float*)d_ws;                 // 8*18*16384*4 = 9.44 MB

    // scratch in d_out (pool fully overwrites d_out last, after conv reads):
    //   xc (NHWC bf16): 8*128*128*256*2 = 67.1 MB at offset 0
    //   wB: 147 KB at byte offset 80 MB
    unsigned short* xcb = (unsigned short*)d_out;
    unsigned short* wB  = (unsigned short*)((char*)d_out + (size_t)80 * 1024 * 1024);

    pasa_wprep<<<dim3(288), dim3(256), 0, stream>>>(w, wB);
    pasa_cvt<<<dim3(2048), dim3(256), 0, stream>>>(x, xcb);
    pasa_conv_mfma<<<dim3(1024), dim3(256), 0, stream>>>(
        xcb, wB, gamma, beta, rmean, rvar, sigma);
    pasa_pool<<<dim3(2048), dim3(256), 0, stream>>>(x, sigma, out);
}